// Round 3
// baseline (250.591 us; speedup 1.0000x reference)
//
#include <hip/hip_runtime.h>
#include <hip/hip_bf16.h>
#include <hip/hip_fp16.h>

typedef _Float16 half8 __attribute__((ext_vector_type(8)));
typedef _Float16 half4v __attribute__((ext_vector_type(4)));
typedef float float4v __attribute__((ext_vector_type(4)));

#define MFMA_F16(a, b, c) __builtin_amdgcn_mfma_f32_16x16x32_f16((a), (b), (c), 0, 0, 0)

#define BATCH 8
#define SEQ   2048
#define DIM   1024
#define QD    128
#define BT    (BATCH * SEQ)          // 16384
#define NSPLIT 4
#define KSPAN (SEQ / NSPLIT)         // 512

// 16-lane (DPP-row) all-lanes max reduction — pure VALU, no LDS pipe.
__device__ __forceinline__ float dpp_max16(float x) {
    int v;
    v = __builtin_amdgcn_update_dpp(0, __float_as_int(x), 0xB1, 0xF, 0xF, false);  // quad_perm [1,0,3,2]
    x = fmaxf(x, __int_as_float(v));
    v = __builtin_amdgcn_update_dpp(0, __float_as_int(x), 0x4E, 0xF, 0xF, false);  // quad_perm [2,3,0,1]
    x = fmaxf(x, __int_as_float(v));
    v = __builtin_amdgcn_update_dpp(0, __float_as_int(x), 0x141, 0xF, 0xF, false); // row_half_mirror
    x = fmaxf(x, __int_as_float(v));
    v = __builtin_amdgcn_update_dpp(0, __float_as_int(x), 0x140, 0xF, 0xF, false); // row_mirror
    x = fmaxf(x, __int_as_float(v));
    return x;
}

// ---------------------------------------------------------------------------
// fp32 -> fp16 converts (BW-bound)
// ---------------------------------------------------------------------------
__global__ __launch_bounds__(256) void cvt_x_kernel(const float* __restrict__ s,
                                                    _Float16* __restrict__ d) {
    int i = blockIdx.x * 256 + threadIdx.x;
    float4 f = ((const float4*)s)[i];
    half4v h = {(_Float16)f.x, (_Float16)f.y, (_Float16)f.z, (_Float16)f.w};
    ((half4v*)d)[i] = h;
}

__global__ __launch_bounds__(256) void cvt_w_kernel(const float* __restrict__ Wq,
                                                    const float* __restrict__ Wk,
                                                    const float* __restrict__ Wv,
                                                    _Float16* __restrict__ Wh) {
    const float* src = (blockIdx.y == 0) ? Wq : ((blockIdx.y == 1) ? Wk : Wv);
    int i = blockIdx.x * 256 + threadIdx.x;
    float4 f = ((const float4*)src)[i];
    half4v h = {(_Float16)f.x, (_Float16)f.y, (_Float16)f.z, (_Float16)f.w};
    ((half4v*)(Wh + (size_t)blockIdx.y * QD * DIM))[i] = h;
}

// ---------------------------------------------------------------------------
// Projection, barrier-free: fragments loaded directly from global (L2-hot).
// Block = 128 rows x 128 cols, 4 waves of 32 rows x 128 cols each.
// ---------------------------------------------------------------------------
__global__ __launch_bounds__(256, 2) void proj_kernel(
    const _Float16* __restrict__ xh,     // (B*T, 1024) fp16
    const _Float16* __restrict__ Wh,     // 3 x (128, 1024) fp16
    _Float16* __restrict__ q_out,
    _Float16* __restrict__ k_out,
    _Float16* __restrict__ vt_out)       // (B, 128, T)
{
    const int tid  = threadIdx.x;
    const int lane = tid & 63;
    const int wave = tid >> 6;
    const int quad = lane >> 4;
    const int l15  = lane & 15;

    const int which = blockIdx.y;
    const _Float16* W = Wh + (size_t)which * QD * DIM;
    const int row0 = blockIdx.x * 128 + wave * 32;   // this wave's 32 rows

    float4v acc[2][8];
#pragma unroll
    for (int rf = 0; rf < 2; rf++)
#pragma unroll
        for (int n = 0; n < 8; n++)
            acc[rf][n] = (float4v){0.f, 0.f, 0.f, 0.f};

    const _Float16* xbase = xh + (size_t)(row0 + l15) * DIM + quad * 8;
    const _Float16* wbase = W + (size_t)l15 * DIM + quad * 8;

    for (int kk = 0; kk < DIM; kk += 32) {
        half8 af[2], bf[8];
#pragma unroll
        for (int rf = 0; rf < 2; rf++)
            af[rf] = *(const half8*)(xbase + (size_t)rf * 16 * DIM + kk);
#pragma unroll
        for (int n = 0; n < 8; n++)
            bf[n] = *(const half8*)(wbase + (size_t)n * 16 * DIM + kk);
#pragma unroll
        for (int rf = 0; rf < 2; rf++)
#pragma unroll
            for (int n = 0; n < 8; n++)
                acc[rf][n] = MFMA_F16(af[rf], bf[n], acc[rf][n]);
    }

    if (which == 2) {
#pragma unroll
        for (int rf = 0; rf < 2; rf++) {
            int grow0 = row0 + rf * 16 + quad * 4;
            int b  = grow0 >> 11;
            int t0 = grow0 & 2047;
#pragma unroll
            for (int n = 0; n < 8; n++) {
                int col = n * 16 + l15;
                half4v h;
#pragma unroll
                for (int r = 0; r < 4; r++) h[r] = (_Float16)acc[rf][n][r];
                *(half4v*)&vt_out[((size_t)(b * QD + col)) * SEQ + t0] = h;
            }
        }
    } else {
        _Float16* out = (which == 0) ? q_out : k_out;
#pragma unroll
        for (int rf = 0; rf < 2; rf++) {
            int grow0 = row0 + rf * 16 + quad * 4;
#pragma unroll
            for (int n = 0; n < 8; n++) {
                int col = n * 16 + l15;
#pragma unroll
                for (int r = 0; r < 4; r++)
                    out[(size_t)(grow0 + r) * QD + col] = (_Float16)acc[rf][n][r];
            }
        }
    }
}

// ---------------------------------------------------------------------------
// Flash attention, barrier-free. Block = 128 q-rows, 4 waves x 32 rows.
// K/V fragments direct from global (L2-resident); LDS only for the
// wave-private P C-layout -> A-layout round-trip. DPP for row reductions.
// Key-split over blockIdx.z; fp16 O-partials + (m,l) for the merge pass.
// ---------------------------------------------------------------------------
__global__ __launch_bounds__(256, 2) void attn_kernel(
    const _Float16* __restrict__ q,    // (B*T, 128)
    const _Float16* __restrict__ k,    // (B*T, 128)
    const _Float16* __restrict__ vt,   // (B, 128, T)
    const int* __restrict__ mask,      // (B*T) 0/1
    _Float16* __restrict__ Op,         // (NSPLIT, B*T, 128) unnormalized partials
    float2* __restrict__ ml)           // (NSPLIT, B*T)
{
    const int LDP = 72;                // 64 + 8 pad halfs
    __shared__ _Float16 Ps[4 * 32 * 72];

    const int tid  = threadIdx.x;
    const int lane = tid & 63;
    const int wave = tid >> 6;
    const int quad = lane >> 4;
    const int l15  = lane & 15;

    const int b  = blockIdx.y;
    const int z  = blockIdx.z;
    const int rowbase = blockIdx.x * 128 + wave * 32;   // wave's 32 q-rows

    // Q fragments resident: A-layout m=l15, k=quad*8+j
    half8 qf[2][4];
#pragma unroll
    for (int rf = 0; rf < 2; rf++) {
        const _Float16* qrow = q + ((size_t)(b * SEQ + rowbase + rf * 16 + l15)) * QD + quad * 8;
#pragma unroll
        for (int kc = 0; kc < 4; kc++)
            qf[rf][kc] = *(const half8*)(qrow + kc * 32);
    }

    const half8 onesv = {(_Float16)1, (_Float16)1, (_Float16)1, (_Float16)1,
                         (_Float16)1, (_Float16)1, (_Float16)1, (_Float16)1};

    float4v oacc[2][8];
#pragma unroll
    for (int rf = 0; rf < 2; rf++)
#pragma unroll
        for (int n = 0; n < 8; n++)
            oacc[rf][n] = (float4v){0.f, 0.f, 0.f, 0.f};
    float4v lacc[2] = {(float4v){0.f, 0.f, 0.f, 0.f}, (float4v){0.f, 0.f, 0.f, 0.f}};
    float mrow[2][4];
#pragma unroll
    for (int rf = 0; rf < 2; rf++)
#pragma unroll
        for (int r = 0; r < 4; r++) mrow[rf][r] = -1e30f;

    _Float16* Pw = &Ps[wave * 32 * LDP];
    const _Float16* kbb = k + ((size_t)(b * SEQ) + l15) * QD + quad * 8;
    const _Float16* vbb = vt + ((size_t)(b * QD) + l15) * SEQ + quad * 8;

    for (int sb = z * KSPAN; sb < z * KSPAN + KSPAN; sb += 64) {
        // masks for this key block (L2-hot dword loads)
        int mk[4];
#pragma unroll
        for (int j = 0; j < 4; j++)
            mk[j] = mask[b * SEQ + sb + j * 16 + l15];

        // S = Q K^T : 32 rows x 64 keys, C layout (col=l15, row=quad*4+r)
        float4v sacc[2][4];
#pragma unroll
        for (int rf = 0; rf < 2; rf++)
#pragma unroll
            for (int j = 0; j < 4; j++)
                sacc[rf][j] = (float4v){0.f, 0.f, 0.f, 0.f};
#pragma unroll
        for (int kc = 0; kc < 4; kc++) {
            half8 kf[4];
#pragma unroll
            for (int j = 0; j < 4; j++)
                kf[j] = *(const half8*)(kbb + (size_t)(sb + j * 16) * QD + kc * 32);
#pragma unroll
            for (int rf = 0; rf < 2; rf++)
#pragma unroll
                for (int j = 0; j < 4; j++)
                    sacc[rf][j] = MFMA_F16(qf[rf][kc], kf[j], sacc[rf][j]);
        }

        // mask + row-max (in-lane over j, DPP over the 16 lanes of the row)
        float alpha[2][4];
#pragma unroll
        for (int rf = 0; rf < 2; rf++) {
            float rmax[4] = {-1e30f, -1e30f, -1e30f, -1e30f};
#pragma unroll
            for (int j = 0; j < 4; j++) {
                bool m_ok = (mk[j] != 0);
#pragma unroll
                for (int r = 0; r < 4; r++) {
                    float s = m_ok ? sacc[rf][j][r] : -1e30f;
                    sacc[rf][j][r] = s;
                    rmax[r] = fmaxf(rmax[r], s);
                }
            }
#pragma unroll
            for (int r = 0; r < 4; r++) {
                float rm = dpp_max16(rmax[r]);
                float mnew = fmaxf(mrow[rf][r], rm);
                alpha[rf][r] = __expf(mrow[rf][r] - mnew);
                mrow[rf][r] = mnew;
            }
        }

        // p = exp(s - m); write to LDS in C-layout, wave-private
#pragma unroll
        for (int rf = 0; rf < 2; rf++)
#pragma unroll
            for (int j = 0; j < 4; j++) {
                int col = j * 16 + l15;
#pragma unroll
                for (int r = 0; r < 4; r++) {
                    float s = sacc[rf][j][r];
                    float p = (s > -1e29f) ? __expf(s - mrow[rf][r]) : 0.f;
                    Pw[(rf * 16 + quad * 4 + r) * LDP + col] = (_Float16)p;
                }
            }

        // rescale accumulators
#pragma unroll
        for (int rf = 0; rf < 2; rf++) {
#pragma unroll
            for (int n = 0; n < 8; n++)
#pragma unroll
                for (int r = 0; r < 4; r++)
                    oacc[rf][n][r] *= alpha[rf][r];
#pragma unroll
            for (int r = 0; r < 4; r++) lacc[rf][r] *= alpha[rf][r];
        }

        // O += P V ; l += P 1. P from LDS (A-layout), V direct from global.
#pragma unroll
        for (int kc = 0; kc < 2; kc++) {
            half8 pf[2];
#pragma unroll
            for (int rf = 0; rf < 2; rf++)
                pf[rf] = *(const half8*)&Pw[(rf * 16 + l15) * LDP + kc * 32 + quad * 8];
#pragma unroll
            for (int n = 0; n < 8; n++) {
                half8 vf = *(const half8*)(vbb + (size_t)(n * 16) * SEQ + sb + kc * 32);
#pragma unroll
                for (int rf = 0; rf < 2; rf++)
                    oacc[rf][n] = MFMA_F16(pf[rf], vf, oacc[rf][n]);
            }
#pragma unroll
            for (int rf = 0; rf < 2; rf++)
                lacc[rf] = MFMA_F16(pf[rf], onesv, lacc[rf]);
        }
    }

    // Epilogue: unnormalized fp16 partials + (m, l)
    _Float16* Oz = Op + (size_t)z * BT * QD;
#pragma unroll
    for (int rf = 0; rf < 2; rf++) {
#pragma unroll
        for (int n = 0; n < 8; n++) {
            int col = n * 16 + l15;
#pragma unroll
            for (int r = 0; r < 4; r++) {
                int row = rowbase + rf * 16 + quad * 4 + r;
                Oz[((size_t)(b * SEQ + row)) * QD + col] = (_Float16)oacc[rf][n][r];
            }
        }
        if (l15 == 0) {
#pragma unroll
            for (int r = 0; r < 4; r++) {
                int row = rowbase + rf * 16 + quad * 4 + r;
                ml[(size_t)z * BT + b * SEQ + row] = make_float2(mrow[rf][r], lacc[rf][r]);
            }
        }
    }
}

// ---------------------------------------------------------------------------
// Merge NSPLIT fp16 partials. 16 threads/row, 8 cols each.
// ---------------------------------------------------------------------------
__global__ __launch_bounds__(256) void merge_kernel(
    const _Float16* __restrict__ Op,   // (NSPLIT, B*T, 128)
    const float2* __restrict__ ml,     // (NSPLIT, B*T)
    float* __restrict__ out)           // (B*T, 128)
{
    int gid = blockIdx.x * 256 + threadIdx.x;   // BT*16 total
    int row = gid >> 4;
    int c8  = (gid & 15) * 8;

    float2 a[NSPLIT];
    float m = -3.0e38f;
#pragma unroll
    for (int s = 0; s < NSPLIT; s++) { a[s] = ml[(size_t)s * BT + row]; m = fmaxf(m, a[s].x); }
    float sc[NSPLIT];
    float denom = 0.f;
#pragma unroll
    for (int s = 0; s < NSPLIT; s++) { sc[s] = __expf(a[s].x - m); denom += sc[s] * a[s].y; }
    float inv = (denom > 0.f) ? (1.0f / denom) : 0.f;

    float acc[8] = {0, 0, 0, 0, 0, 0, 0, 0};
#pragma unroll
    for (int s = 0; s < NSPLIT; s++) {
        half8 o = *(const half8*)&Op[(size_t)s * BT * QD + (size_t)row * QD + c8];
#pragma unroll
        for (int e = 0; e < 8; e++) acc[e] += (float)o[e] * sc[s];
    }
    float4 lo = make_float4(acc[0] * inv, acc[1] * inv, acc[2] * inv, acc[3] * inv);
    float4 hi = make_float4(acc[4] * inv, acc[5] * inv, acc[6] * inv, acc[7] * inv);
    *(float4*)&out[(size_t)row * QD + c8] = lo;
    *(float4*)&out[(size_t)row * QD + c8 + 4] = hi;
}

extern "C" void kernel_launch(void* const* d_in, const int* in_sizes, int n_in,
                              void* d_out, int out_size, void* d_ws, size_t ws_size,
                              hipStream_t stream) {
    const float* x    = (const float*)d_in[0];
    const int*   mask = (const int*)d_in[1];
    const float* Wq   = (const float*)d_in[2];
    const float* Wk   = (const float*)d_in[3];
    const float* Wv   = (const float*)d_in[4];
    float* out = (float*)d_out;

    char* p = (char*)d_ws;
    _Float16* xh  = (_Float16*)p; p += (size_t)BT * DIM * 2;        // 32 MB
    _Float16* Wh  = (_Float16*)p; p += (size_t)3 * QD * DIM * 2;    // 768 KB
    _Float16* qb  = (_Float16*)p; p += (size_t)BT * QD * 2;         // 4 MB
    _Float16* kb  = (_Float16*)p; p += (size_t)BT * QD * 2;         // 4 MB
    _Float16* vtb = (_Float16*)p; p += (size_t)BT * QD * 2;         // 4 MB
    _Float16* Op  = (_Float16*)p; p += (size_t)NSPLIT * BT * QD * 2;// 16 MB
    float2*   ml  = (float2*)p;                                     // 512 KB

    cvt_x_kernel<<<dim3(BT * DIM / 4 / 256), 256, 0, stream>>>(x, xh);
    cvt_w_kernel<<<dim3(QD * DIM / 4 / 256, 3), 256, 0, stream>>>(Wq, Wk, Wv, Wh);
    proj_kernel<<<dim3(BT / 128, 3), 256, 0, stream>>>(xh, Wh, qb, kb, vtb);
    attn_kernel<<<dim3(SEQ / 128, BATCH, NSPLIT), 256, 0, stream>>>(qb, kb, vtb, mask, Op, ml);
    merge_kernel<<<dim3(BT * 16 / 256), 256, 0, stream>>>(Op, ml, out);
}

// Round 4
// 163.440 us; speedup vs baseline: 1.5332x; 1.5332x over previous
//
#include <hip/hip_runtime.h>
#include <hip/hip_bf16.h>
#include <hip/hip_fp16.h>

typedef _Float16 half8 __attribute__((ext_vector_type(8)));
typedef _Float16 half4v __attribute__((ext_vector_type(4)));
typedef float float4v __attribute__((ext_vector_type(4)));

#define MFMA_F16(a, b, c) __builtin_amdgcn_mfma_f32_16x16x32_f16((a), (b), (c), 0, 0, 0)

// Async global->LDS DMA, 16B per lane. LDS dest = wave-uniform base + lane*16.
#define GLDS16(gp, lp) \
    __builtin_amdgcn_global_load_lds((const __attribute__((address_space(1))) unsigned int*)(gp), \
                                     (__attribute__((address_space(3))) unsigned int*)(lp), 16, 0, 0)

#define BATCH 8
#define SEQ   2048
#define DIM   1024
#define QD    128
#define BT    (BATCH * SEQ)          // 16384
#define NSPLIT 4
#define KSPAN (SEQ / NSPLIT)         // 512

// 16-lane all-lanes max reduction via DPP — pure VALU, stays off the LDS pipe.
__device__ __forceinline__ float dpp_max16(float x) {
    int v;
    v = __builtin_amdgcn_update_dpp(0, __float_as_int(x), 0xB1, 0xF, 0xF, false);  // quad_perm [1,0,3,2]
    x = fmaxf(x, __int_as_float(v));
    v = __builtin_amdgcn_update_dpp(0, __float_as_int(x), 0x4E, 0xF, 0xF, false);  // quad_perm [2,3,0,1]
    x = fmaxf(x, __int_as_float(v));
    v = __builtin_amdgcn_update_dpp(0, __float_as_int(x), 0x141, 0xF, 0xF, false); // row_half_mirror
    x = fmaxf(x, __int_as_float(v));
    v = __builtin_amdgcn_update_dpp(0, __float_as_int(x), 0x140, 0xF, 0xF, false); // row_mirror
    x = fmaxf(x, __int_as_float(v));
    return x;
}

// ---------------------------------------------------------------------------
// fp32 -> fp16 converts (BW-bound)
// ---------------------------------------------------------------------------
__global__ __launch_bounds__(256) void cvt_x_kernel(const float* __restrict__ s,
                                                    _Float16* __restrict__ d) {
    int i = blockIdx.x * 256 + threadIdx.x;
    float4 f = ((const float4*)s)[i];
    half4v h = {(_Float16)f.x, (_Float16)f.y, (_Float16)f.z, (_Float16)f.w};
    ((half4v*)d)[i] = h;
}

__global__ __launch_bounds__(256) void cvt_w_kernel(const float* __restrict__ Wq,
                                                    const float* __restrict__ Wk,
                                                    const float* __restrict__ Wv,
                                                    _Float16* __restrict__ Wh) {
    const float* src = (blockIdx.y == 0) ? Wq : ((blockIdx.y == 1) ? Wk : Wv);
    int i = blockIdx.x * 256 + threadIdx.x;
    float4 f = ((const float4*)src)[i];
    half4v h = {(_Float16)f.x, (_Float16)f.y, (_Float16)f.z, (_Float16)f.w};
    ((half4v*)(Wh + (size_t)blockIdx.y * QD * DIM))[i] = h;
}

// ---------------------------------------------------------------------------
// Projection: m97-style. 64x128 tile, BK=64, global_load_lds staging into
// XOR-swizzled LDS (group ^= row&7 at 8-half granularity -> 2-way-only bank
// aliasing on ds_read_b128 fragment reads, which is free).
// Grid 256 x 3 = 768 blocks = exactly 3/CU, no tail.
// ---------------------------------------------------------------------------
__global__ __launch_bounds__(256, 3) void proj_kernel(
    const _Float16* __restrict__ xh,     // (B*T, 1024)
    const _Float16* __restrict__ Wh,     // 3 x (128, 1024)
    _Float16* __restrict__ q_out,        // (B*T, 128)
    _Float16* __restrict__ k_out,        // (B*T, 128)
    _Float16* __restrict__ vt_out)       // (B, 128, T)
{
    __shared__ _Float16 As[64 * 64];     // 8 KB, swizzled row-major 64 x 64
    __shared__ _Float16 Bs[128 * 64];    // 16 KB

    const int tid  = threadIdx.x;
    const int lane = tid & 63;
    const int wave = tid >> 6;
    const int quad = lane >> 4;
    const int l15  = lane & 15;
    const int wr   = wave >> 1;          // 0..1 : row half (32 rows)
    const int wc   = wave & 1;           // 0..1 : col half (64 cols)

    const int which = blockIdx.y;
    const _Float16* W = Wh + (size_t)which * QD * DIM;
    const int row0 = blockIdx.x * 64;

    float4v acc[2][4];
#pragma unroll
    for (int rf = 0; rf < 2; rf++)
#pragma unroll
        for (int n = 0; n < 4; n++)
            acc[rf][n] = (float4v){0.f, 0.f, 0.f, 0.f};

    for (int kk = 0; kk < DIM; kk += 64) {
        __syncthreads();
        // A: 512 chunks of 16B; 2 DMA calls per wave.
#pragma unroll
        for (int c = 0; c < 2; c++) {
            int ci = wave * 128 + c * 64 + lane;          // 0..511
            int r  = ci >> 3;
            int g  = (ci & 7) ^ (r & 7);                  // un-swizzle on the global side
            GLDS16(xh + (size_t)(row0 + r) * DIM + kk + g * 8, &As[(wave * 128 + c * 64) * 8]);
        }
        // B: 1024 chunks; 4 DMA calls per wave.
#pragma unroll
        for (int c = 0; c < 4; c++) {
            int ci = wave * 256 + c * 64 + lane;          // 0..1023
            int r  = ci >> 3;
            int g  = (ci & 7) ^ (r & 7);
            GLDS16(W + (size_t)r * DIM + kk + g * 8, &Bs[(wave * 256 + c * 64) * 8]);
        }
        __syncthreads();

        half8 af[2][2], bf[4][2];
#pragma unroll
        for (int rf = 0; rf < 2; rf++)
#pragma unroll
            for (int kc = 0; kc < 2; kc++) {
                int r = wr * 32 + rf * 16 + l15;
                int g = (kc * 4 + quad) ^ (r & 7);
                af[rf][kc] = *(const half8*)&As[r * 64 + g * 8];
            }
#pragma unroll
        for (int n = 0; n < 4; n++)
#pragma unroll
            for (int kc = 0; kc < 2; kc++) {
                int r = wc * 64 + n * 16 + l15;
                int g = (kc * 4 + quad) ^ (r & 7);
                bf[n][kc] = *(const half8*)&Bs[r * 64 + g * 8];
            }
#pragma unroll
        for (int kc = 0; kc < 2; kc++)
#pragma unroll
            for (int rf = 0; rf < 2; rf++)
#pragma unroll
                for (int n = 0; n < 4; n++)
                    acc[rf][n] = MFMA_F16(af[rf][kc], bf[n][kc], acc[rf][n]);
    }

    // Epilogue. C layout: col = l15, row = quad*4 + reg.
    if (which == 2) {
#pragma unroll
        for (int rf = 0; rf < 2; rf++) {
            int grow0 = row0 + wr * 32 + rf * 16 + quad * 4;
            int b  = grow0 >> 11;
            int t0 = grow0 & 2047;
#pragma unroll
            for (int n = 0; n < 4; n++) {
                int col = wc * 64 + n * 16 + l15;
                half4v h;
#pragma unroll
                for (int r = 0; r < 4; r++) h[r] = (_Float16)acc[rf][n][r];
                *(half4v*)&vt_out[((size_t)(b * QD + col)) * SEQ + t0] = h;
            }
        }
    } else {
        _Float16* out = (which == 0) ? q_out : k_out;
#pragma unroll
        for (int rf = 0; rf < 2; rf++) {
            int grow0 = row0 + wr * 32 + rf * 16 + quad * 4;
#pragma unroll
            for (int n = 0; n < 4; n++) {
                int col = wc * 64 + n * 16 + l15;
#pragma unroll
                for (int r = 0; r < 4; r++)
                    out[(size_t)(grow0 + r) * QD + col] = (_Float16)acc[rf][n][r];
            }
        }
    }
}

// ---------------------------------------------------------------------------
// Flash attention. Block = 128 q-rows (4 waves x 32 rows), key blocks of 64,
// key-split over blockIdx.z. K/V staged via global_load_lds into XOR-swizzled
// LDS; P round-trip also swizzled. DPP row reductions; ones-column MFMA for l;
// fp16 unnormalized partials + (m,l) for merge.
// ---------------------------------------------------------------------------
__global__ __launch_bounds__(256, 2) void attn_kernel(
    const _Float16* __restrict__ q,    // (B*T, 128)
    const _Float16* __restrict__ k,    // (B*T, 128)
    const _Float16* __restrict__ vt,   // (B, 128, T)
    const int* __restrict__ mask,      // (B*T)
    _Float16* __restrict__ Op,         // (NSPLIT, B*T, 128)
    float2* __restrict__ ml)           // (NSPLIT, B*T)
{
    __shared__ _Float16 Ks[64 * 128];      // 16 KB swizzled: keys x 128d
    __shared__ _Float16 Vs[128 * 64];      // 16 KB swizzled: 128d x keys
    __shared__ _Float16 Ps[4 * 32 * 64];   // 16 KB swizzled, wave-private slabs
    __shared__ int Ms[64];

    const int tid  = threadIdx.x;
    const int lane = tid & 63;
    const int wave = tid >> 6;
    const int quad = lane >> 4;
    const int l15  = lane & 15;

    const int b  = blockIdx.y;
    const int z  = blockIdx.z;
    const int rowbase = blockIdx.x * 128 + wave * 32;

    half8 qf[2][4];
#pragma unroll
    for (int rf = 0; rf < 2; rf++) {
        const _Float16* qrow = q + ((size_t)(b * SEQ + rowbase + rf * 16 + l15)) * QD + quad * 8;
#pragma unroll
        for (int kc = 0; kc < 4; kc++)
            qf[rf][kc] = *(const half8*)(qrow + kc * 32);
    }

    const half8 onesv = {(_Float16)1, (_Float16)1, (_Float16)1, (_Float16)1,
                         (_Float16)1, (_Float16)1, (_Float16)1, (_Float16)1};

    float4v oacc[2][8];
#pragma unroll
    for (int rf = 0; rf < 2; rf++)
#pragma unroll
        for (int n = 0; n < 8; n++)
            oacc[rf][n] = (float4v){0.f, 0.f, 0.f, 0.f};
    float4v lacc[2] = {(float4v){0.f, 0.f, 0.f, 0.f}, (float4v){0.f, 0.f, 0.f, 0.f}};
    float mrow[2][4];
#pragma unroll
    for (int rf = 0; rf < 2; rf++)
#pragma unroll
        for (int r = 0; r < 4; r++) mrow[rf][r] = -1e30f;

    _Float16* Pw = &Ps[wave * 32 * 64];

    for (int sb = z * KSPAN; sb < z * KSPAN + KSPAN; sb += 64) {
        __syncthreads();
        // K: 64 keys x 128d = 1024 chunks; 4 DMA calls/wave, swizzled dest.
#pragma unroll
        for (int c = 0; c < 4; c++) {
            int ci = wave * 256 + c * 64 + lane;
            int r  = ci >> 4;                       // key
            int gs = ci & 15;
            int g  = (gs & 8) | ((gs ^ r) & 7);     // global group for this LDS slot
            GLDS16(k + ((size_t)(b * SEQ + sb + r)) * QD + g * 8, &Ks[(wave * 256 + c * 64) * 8]);
        }
        // V^T: 128d x 64 keys = 1024 chunks; 4 DMA calls/wave.
#pragma unroll
        for (int c = 0; c < 4; c++) {
            int ci = wave * 256 + c * 64 + lane;
            int r  = ci >> 3;                       // d
            int g  = ((ci & 7) ^ r) & 7;
            GLDS16(vt + ((size_t)(b * QD + r)) * SEQ + sb + g * 8, &Vs[(wave * 256 + c * 64) * 8]);
        }
        if (tid < 64) Ms[tid] = mask[b * SEQ + sb + tid];
        __syncthreads();

        // S = Q K^T : 32 rows x 64 keys per wave, C layout
        float4v sacc[2][4];
#pragma unroll
        for (int rf = 0; rf < 2; rf++)
#pragma unroll
            for (int j = 0; j < 4; j++)
                sacc[rf][j] = (float4v){0.f, 0.f, 0.f, 0.f};
#pragma unroll
        for (int kc = 0; kc < 4; kc++) {
            half8 kf[4];
#pragma unroll
            for (int j = 0; j < 4; j++) {
                int r  = j * 16 + l15;
                int g  = kc * 4 + quad;
                int gs = (g & 8) | ((g ^ r) & 7);
                kf[j] = *(const half8*)&Ks[r * 128 + gs * 8];
            }
#pragma unroll
            for (int rf = 0; rf < 2; rf++)
#pragma unroll
                for (int j = 0; j < 4; j++)
                    sacc[rf][j] = MFMA_F16(qf[rf][kc], kf[j], sacc[rf][j]);
        }

        // mask + row-max + online-softmax scale
        float alpha[2][4];
#pragma unroll
        for (int rf = 0; rf < 2; rf++) {
            float rmax[4] = {-1e30f, -1e30f, -1e30f, -1e30f};
#pragma unroll
            for (int j = 0; j < 4; j++) {
                bool m_ok = (Ms[j * 16 + l15] != 0);
#pragma unroll
                for (int r = 0; r < 4; r++) {
                    float s = m_ok ? sacc[rf][j][r] : -1e30f;
                    sacc[rf][j][r] = s;
                    rmax[r] = fmaxf(rmax[r], s);
                }
            }
#pragma unroll
            for (int r = 0; r < 4; r++) {
                float rm = dpp_max16(rmax[r]);
                float mnew = fmaxf(mrow[rf][r], rm);
                alpha[rf][r] = __expf(mrow[rf][r] - mnew);
                mrow[rf][r] = mnew;
            }
        }

        // p = exp(s - m) -> wave-private swizzled LDS (C-layout write)
#pragma unroll
        for (int rf = 0; rf < 2; rf++)
#pragma unroll
            for (int j = 0; j < 4; j++) {
                int col = j * 16 + l15;
                int gc  = col >> 3;
#pragma unroll
                for (int r = 0; r < 4; r++) {
                    int m  = rf * 16 + quad * 4 + r;
                    int gs = (gc ^ m) & 7;
                    float s = sacc[rf][j][r];
                    float p = (s > -1e29f) ? __expf(s - mrow[rf][r]) : 0.f;
                    Pw[m * 64 + gs * 8 + (col & 7)] = (_Float16)p;
                }
            }

        // rescale accumulators
#pragma unroll
        for (int rf = 0; rf < 2; rf++) {
#pragma unroll
            for (int n = 0; n < 8; n++)
#pragma unroll
                for (int r = 0; r < 4; r++)
                    oacc[rf][n][r] *= alpha[rf][r];
#pragma unroll
            for (int r = 0; r < 4; r++) lacc[rf][r] *= alpha[rf][r];
        }

        // O += P V ; l += P 1
#pragma unroll
        for (int kc = 0; kc < 2; kc++) {
            half8 pf[2];
#pragma unroll
            for (int rf = 0; rf < 2; rf++) {
                int m  = rf * 16 + l15;
                int gs = ((kc * 4 + quad) ^ m) & 7;
                pf[rf] = *(const half8*)&Pw[m * 64 + gs * 8];
            }
#pragma unroll
            for (int n = 0; n < 8; n++) {
                int r  = n * 16 + l15;
                int gs = ((kc * 4 + quad) ^ r) & 7;
                half8 vf = *(const half8*)&Vs[r * 64 + gs * 8];
#pragma unroll
                for (int rf = 0; rf < 2; rf++)
                    oacc[rf][n] = MFMA_F16(pf[rf], vf, oacc[rf][n]);
            }
#pragma unroll
            for (int rf = 0; rf < 2; rf++)
                lacc[rf] = MFMA_F16(pf[rf], onesv, lacc[rf]);
        }
    }

    // Epilogue: fp16 unnormalized partials + (m, l)
    _Float16* Oz = Op + (size_t)z * BT * QD;
#pragma unroll
    for (int rf = 0; rf < 2; rf++) {
#pragma unroll
        for (int n = 0; n < 8; n++) {
            int col = n * 16 + l15;
#pragma unroll
            for (int r = 0; r < 4; r++) {
                int row = rowbase + rf * 16 + quad * 4 + r;
                Oz[((size_t)(b * SEQ + row)) * QD + col] = (_Float16)oacc[rf][n][r];
            }
        }
        if (l15 == 0) {
#pragma unroll
            for (int r = 0; r < 4; r++) {
                int row = rowbase + rf * 16 + quad * 4 + r;
                ml[(size_t)z * BT + b * SEQ + row] = make_float2(mrow[rf][r], lacc[rf][r]);
            }
        }
    }
}

// ---------------------------------------------------------------------------
// Merge NSPLIT fp16 partials. 16 threads/row, 8 cols each.
// ---------------------------------------------------------------------------
__global__ __launch_bounds__(256) void merge_kernel(
    const _Float16* __restrict__ Op,
    const float2* __restrict__ ml,
    float* __restrict__ out)
{
    int gid = blockIdx.x * 256 + threadIdx.x;
    int row = gid >> 4;
    int c8  = (gid & 15) * 8;

    float2 a[NSPLIT];
    float m = -3.0e38f;
#pragma unroll
    for (int s = 0; s < NSPLIT; s++) { a[s] = ml[(size_t)s * BT + row]; m = fmaxf(m, a[s].x); }
    float sc[NSPLIT];
    float denom = 0.f;
#pragma unroll
    for (int s = 0; s < NSPLIT; s++) { sc[s] = __expf(a[s].x - m); denom += sc[s] * a[s].y; }
    float inv = (denom > 0.f) ? (1.0f / denom) : 0.f;

    float acc[8] = {0, 0, 0, 0, 0, 0, 0, 0};
#pragma unroll
    for (int s = 0; s < NSPLIT; s++) {
        half8 o = *(const half8*)&Op[(size_t)s * BT * QD + (size_t)row * QD + c8];
#pragma unroll
        for (int e = 0; e < 8; e++) acc[e] += (float)o[e] * sc[s];
    }
    float4 lo = make_float4(acc[0] * inv, acc[1] * inv, acc[2] * inv, acc[3] * inv);
    float4 hi = make_float4(acc[4] * inv, acc[5] * inv, acc[6] * inv, acc[7] * inv);
    *(float4*)&out[(size_t)row * QD + c8] = lo;
    *(float4*)&out[(size_t)row * QD + c8 + 4] = hi;
}

extern "C" void kernel_launch(void* const* d_in, const int* in_sizes, int n_in,
                              void* d_out, int out_size, void* d_ws, size_t ws_size,
                              hipStream_t stream) {
    const float* x    = (const float*)d_in[0];
    const int*   mask = (const int*)d_in[1];
    const float* Wq   = (const float*)d_in[2];
    const float* Wk   = (const float*)d_in[3];
    const float* Wv   = (const float*)d_in[4];
    float* out = (float*)d_out;

    char* p = (char*)d_ws;
    _Float16* xh  = (_Float16*)p; p += (size_t)BT * DIM * 2;        // 32 MB
    _Float16* Wh  = (_Float16*)p; p += (size_t)3 * QD * DIM * 2;    // 768 KB
    _Float16* qb  = (_Float16*)p; p += (size_t)BT * QD * 2;         // 4 MB
    _Float16* kb  = (_Float16*)p; p += (size_t)BT * QD * 2;         // 4 MB
    _Float16* vtb = (_Float16*)p; p += (size_t)BT * QD * 2;         // 4 MB
    _Float16* Op  = (_Float16*)p; p += (size_t)NSPLIT * BT * QD * 2;// 16 MB
    float2*   ml  = (float2*)p;                                     // 512 KB

    cvt_x_kernel<<<dim3(BT * DIM / 4 / 256), 256, 0, stream>>>(x, xh);
    cvt_w_kernel<<<dim3(QD * DIM / 4 / 256, 3), 256, 0, stream>>>(Wq, Wk, Wv, Wh);
    proj_kernel<<<dim3(BT / 64, 3), 256, 0, stream>>>(xh, Wh, qb, kb, vtb);
    attn_kernel<<<dim3(SEQ / 128, BATCH, NSPLIT), 256, 0, stream>>>(qb, kb, vtb, mask, Op, ml);
    merge_kernel<<<dim3(BT * 16 / 256), 256, 0, stream>>>(Op, ml, out);
}